// Round 3
// baseline (368.660 us; speedup 1.0000x reference)
//
#include <hip/hip_runtime.h>

#define NPTS 1024
#define NC 256
#define NH 360
#define NW 360
#define NHW (NH * NW)
#define NCHW (NC * NHW)
#define PPB 4       // points per block; 512 single-wave blocks = 2 blocks/CU

// ---------------------------------------------------------------------------
// Kernel 1: fused gather + 3-layer MLP, ONE WAVE per block (64 threads).
// Thread l owns 4 output columns (4l..4l+3) for all 4 points of the quad:
//  - per c: ONE ds_read_b128 broadcast (activation quad) + ONE per-lane b128
//    weight load + 16 FMA  -> VALU-balanced, LDS-pipe load cut 4x vs the
//    thread-per-column mapping (no more 4 waves reading identical streams)
//  - w1 still read exactly once per quad -> L2 weight traffic unchanged
//  - single-wave block: NO __syncthreads; LDS RAW hazards resolved by
//    wave-synchronous lgkmcnt waits
// Writes pq[2048][32]: rows 0..1023 = f1 @ w3, rows 1024..2047 = b3 - f2 @ w3.
// ---------------------------------------------------------------------------
__global__ __launch_bounds__(64) void mlp_kernel(
    const float* __restrict__ feature,
    const int* __restrict__ idx1,
    const int* __restrict__ idx2,
    const float* __restrict__ w1, const float* __restrict__ b1,
    const float* __restrict__ w2, const float* __restrict__ b2,
    const float* __restrict__ w3, const float* __restrict__ b3,
    float* __restrict__ pq)
{
    __shared__ float4 Xs[256];    // [c] -> 4 points, 4 KB
    __shared__ float4 H1s[256];   // [j] -> 4 points, 4 KB
    __shared__ float4 F2s[128];   // [j] -> 4 points, 2 KB

    const int l = threadIdx.x;        // 0..63
    const int base = blockIdx.x * PPB;

    // ---- fused gather: thread l gathers channels {l, l+64, l+128, l+192} ----
    // 16 independent scattered loads, non-temporal (zero-reuse lines; don't
    // evict the hot weight set from L2).
    {
        const int col0 = base & (NPTS - 1);              // multiple of 4
        const int* idx = (base < NPTS) ? idx1 : idx2;    // uniform per block
        const int4 bb4 = *(const int4*)(idx + col0);
        const int4 hh4 = *(const int4*)(idx + NPTS + col0);
        const int4 ww4 = *(const int4*)(idx + 2 * NPTS + col0);
        const size_t p0 = (size_t)bb4.x * NCHW + (size_t)(hh4.x * NW + ww4.x);
        const size_t p1 = (size_t)bb4.y * NCHW + (size_t)(hh4.y * NW + ww4.y);
        const size_t p2 = (size_t)bb4.z * NCHW + (size_t)(hh4.z * NW + ww4.z);
        const size_t p3 = (size_t)bb4.w * NCHW + (size_t)(hh4.w * NW + ww4.w);
        #pragma unroll
        for (int k = 0; k < 4; ++k) {
            const int c = l + 64 * k;
            const size_t coff = (size_t)c * NHW;
            float4 v;
            v.x = __builtin_nontemporal_load(feature + p0 + coff);
            v.y = __builtin_nontemporal_load(feature + p1 + coff);
            v.z = __builtin_nontemporal_load(feature + p2 + coff);
            v.w = __builtin_nontemporal_load(feature + p3 + coff);
            Xs[c] = v;                                   // b128 write
        }
    }
    // single wave: lgkmcnt/vmcnt ordering suffices, no barrier

    // ---- layer 1: 256 -> 256. lane l -> cols 4l..4l+3, 4 points each ----
    {
        const float4* w1v = (const float4*)w1;    // w1[c][4l..4l+3]
        float4 a0 = {0,0,0,0}, a1 = {0,0,0,0}, a2 = {0,0,0,0}, a3 = {0,0,0,0};
        #pragma unroll 8
        for (int c = 0; c < 256; ++c) {
            const float4 x = Xs[c];               // ds_read_b128 broadcast
            const float4 w = w1v[c * 64 + l];     // 16 B/lane, coalesced
            a0.x = fmaf(x.x, w.x, a0.x); a0.y = fmaf(x.y, w.x, a0.y);
            a0.z = fmaf(x.z, w.x, a0.z); a0.w = fmaf(x.w, w.x, a0.w);
            a1.x = fmaf(x.x, w.y, a1.x); a1.y = fmaf(x.y, w.y, a1.y);
            a1.z = fmaf(x.z, w.y, a1.z); a1.w = fmaf(x.w, w.y, a1.w);
            a2.x = fmaf(x.x, w.z, a2.x); a2.y = fmaf(x.y, w.z, a2.y);
            a2.z = fmaf(x.z, w.z, a2.z); a2.w = fmaf(x.w, w.z, a2.w);
            a3.x = fmaf(x.x, w.w, a3.x); a3.y = fmaf(x.y, w.w, a3.y);
            a3.z = fmaf(x.z, w.w, a3.z); a3.w = fmaf(x.w, w.w, a3.w);
        }
        const float4 bb = ((const float4*)b1)[l];
        float4 h;
        h.x = fmaxf(a0.x + bb.x, 0.f); h.y = fmaxf(a0.y + bb.x, 0.f);
        h.z = fmaxf(a0.z + bb.x, 0.f); h.w = fmaxf(a0.w + bb.x, 0.f);
        H1s[4 * l + 0] = h;
        h.x = fmaxf(a1.x + bb.y, 0.f); h.y = fmaxf(a1.y + bb.y, 0.f);
        h.z = fmaxf(a1.z + bb.y, 0.f); h.w = fmaxf(a1.w + bb.y, 0.f);
        H1s[4 * l + 1] = h;
        h.x = fmaxf(a2.x + bb.z, 0.f); h.y = fmaxf(a2.y + bb.z, 0.f);
        h.z = fmaxf(a2.z + bb.z, 0.f); h.w = fmaxf(a2.w + bb.z, 0.f);
        H1s[4 * l + 2] = h;
        h.x = fmaxf(a3.x + bb.w, 0.f); h.y = fmaxf(a3.y + bb.w, 0.f);
        h.z = fmaxf(a3.z + bb.w, 0.f); h.w = fmaxf(a3.w + bb.w, 0.f);
        H1s[4 * l + 3] = h;
    }

    // ---- layer 2: 256 -> 128. lane l -> cols 2l..2l+1, 4 points each ----
    {
        const float2* w2v = (const float2*)w2;    // w2[c][2l..2l+1]
        float4 a0 = {0,0,0,0}, a1 = {0,0,0,0};
        #pragma unroll 8
        for (int c = 0; c < 256; ++c) {
            const float4 x = H1s[c];              // ds_read_b128 broadcast
            const float2 w = w2v[c * 64 + l];     // 8 B/lane, coalesced
            a0.x = fmaf(x.x, w.x, a0.x); a0.y = fmaf(x.y, w.x, a0.y);
            a0.z = fmaf(x.z, w.x, a0.z); a0.w = fmaf(x.w, w.x, a0.w);
            a1.x = fmaf(x.x, w.y, a1.x); a1.y = fmaf(x.y, w.y, a1.y);
            a1.z = fmaf(x.z, w.y, a1.z); a1.w = fmaf(x.w, w.y, a1.w);
        }
        const float2 bb = ((const float2*)b2)[l];
        float4 h;
        h.x = fmaxf(a0.x + bb.x, 0.f); h.y = fmaxf(a0.y + bb.x, 0.f);
        h.z = fmaxf(a0.z + bb.x, 0.f); h.w = fmaxf(a0.w + bb.x, 0.f);
        F2s[2 * l + 0] = h;
        h.x = fmaxf(a1.x + bb.y, 0.f); h.y = fmaxf(a1.y + bb.y, 0.f);
        h.z = fmaxf(a1.z + bb.y, 0.f); h.w = fmaxf(a1.w + bb.y, 0.f);
        F2s[2 * l + 1] = h;
    }

    // ---- layer 3 (no relu): lane l -> col j=l&31, point-pair l>>5 ----
    {
        const int j = l & 31;
        const int gh = l >> 5;                    // 0: points 0,1; 1: points 2,3
        const float* F2f = (const float*)F2s;
        float2 acc = {0.f, 0.f};
        #pragma unroll 8
        for (int c = 0; c < 128; ++c) {
            const float2 x = *(const float2*)&F2f[c * 4 + 2 * gh];  // b64, 2-way bcast
            const float w = w3[c * 32 + j];
            acc.x = fmaf(x.x, w, acc.x);
            acc.y = fmaf(x.y, w, acc.y);
        }
        const int pA = base + 2 * gh;
        if (base < NPTS) {
            pq[(size_t)pA * 32 + j]       = acc.x;
            pq[(size_t)(pA + 1) * 32 + j] = acc.y;
        } else {
            const float bj = b3[j];
            pq[(size_t)pA * 32 + j]       = bj - acc.x;
            pq[(size_t)(pA + 1) * 32 + j] = bj - acc.y;
        }
    }
}

// ---------------------------------------------------------------------------
// Kernel 2: out[m][n] = b4 + sum_k w4[k] * relu(p1[m][k] + q2[n][k])
// Grid: (4 n-tiles, 128 m-tiles) = 512 blocks, 256 threads (one n, 8 m's).
// P-rows and w4 are block-uniform -> scalar (SGPR) loads; q in VGPRs.
// Inner loop is 3 VALU ops / element, zero LDS, no barriers. (~VALU floor)
// ---------------------------------------------------------------------------
#define MT 8

__global__ __launch_bounds__(256) void pair_kernel(
    const float* __restrict__ pq,
    const float* __restrict__ w4,
    const float* __restrict__ b4,
    float* __restrict__ out)
{
    const int tid = threadIdx.x;
    const int n = blockIdx.x * 256 + tid;
    const int m0 = blockIdx.y * MT;

    // q[n][0..31] in registers via 8x dwordx4
    float q[32];
    const float4* q4 = (const float4*)(pq + (size_t)(NPTS + n) * 32);
    #pragma unroll
    for (int k8 = 0; k8 < 8; ++k8) {
        float4 t = q4[k8];
        q[4 * k8 + 0] = t.x;
        q[4 * k8 + 1] = t.y;
        q[4 * k8 + 2] = t.z;
        q[4 * k8 + 3] = t.w;
    }
    const float b4v = b4[0];          // uniform -> SGPR

    #pragma unroll
    for (int mm = 0; mm < MT; ++mm) {
        const float* Pm = pq + (size_t)(m0 + mm) * 32;   // uniform row -> s_load
        float a = b4v;
        #pragma unroll
        for (int k = 0; k < 32; ++k) {
            float t = Pm[k] + q[k];                      // v_add (sgpr + vgpr)
            a = fmaf(w4[k], fmaxf(t, 0.f), a);           // v_max, v_fma (sgpr mul)
        }
        out[(size_t)(m0 + mm) * 1024 + n] = a;           // coalesced over n
    }
}

extern "C" void kernel_launch(void* const* d_in, const int* in_sizes, int n_in,
                              void* d_out, int out_size, void* d_ws, size_t ws_size,
                              hipStream_t stream) {
    const float* feature = (const float*)d_in[0];
    const int*   idx1    = (const int*)d_in[1];
    const int*   idx2    = (const int*)d_in[2];
    const float* w1      = (const float*)d_in[3];
    const float* b1      = (const float*)d_in[4];
    const float* w2      = (const float*)d_in[5];
    const float* b2      = (const float*)d_in[6];
    const float* w3      = (const float*)d_in[7];
    const float* b3      = (const float*)d_in[8];
    const float* w4      = (const float*)d_in[9];
    const float* b4      = (const float*)d_in[10];
    float* out = (float*)d_out;

    float* pq = (float*)d_ws;                       // 2048*32*4 = 256 KB

    mlp_kernel<<<2048 / PPB, 64, 0, stream>>>(
        feature, idx1, idx2, w1, b1, w2, b2, w3, b3, pq);

    pair_kernel<<<dim3(4, 128), 256, 0, stream>>>(pq, w4, b4, out);
}

// Round 4
// 363.051 us; speedup vs baseline: 1.0155x; 1.0155x over previous
//
#include <hip/hip_runtime.h>

#define NPTS 1024
#define NC 256
#define NH 360
#define NW 360
#define NHW (NH * NW)
#define NCHW (NC * NHW)

typedef float v2f __attribute__((ext_vector_type(2)));

// ---------------------------------------------------------------------------
// Kernel A: pure scatter-gather. 512 blocks x 256 threads, one quad/block.
// Thread c loads feature[b_p, c, h_p, w_p] for the quad's 4 points (all
// independent, 1024 loads in flight per block) and writes Xq[quad][c][0..3]
// as one b128 store (wave-contiguous). Decoupling this latency-bound phase
// from the MLP lets it run at the random-HBM-line floor with nothing else
// in the critical path.
// ---------------------------------------------------------------------------
__global__ __launch_bounds__(256) void gather_kernel(
    const float* __restrict__ feature,
    const int* __restrict__ idx1,
    const int* __restrict__ idx2,
    float4* __restrict__ Xq)
{
    const int c = threadIdx.x;
    const int quad = blockIdx.x;
    const int base = quad * 4;
    const int col0 = base & (NPTS - 1);              // multiple of 4
    const int* idx = (base < NPTS) ? idx1 : idx2;    // uniform per block
    const int4 bb4 = *(const int4*)(idx + col0);
    const int4 hh4 = *(const int4*)(idx + NPTS + col0);
    const int4 ww4 = *(const int4*)(idx + 2 * NPTS + col0);
    const size_t coff = (size_t)c * NHW;
    float4 v;
    // non-temporal: zero-reuse scattered lines; keep weights hot in L2
    v.x = __builtin_nontemporal_load(
              feature + (size_t)bb4.x * NCHW + coff + (size_t)(hh4.x * NW + ww4.x));
    v.y = __builtin_nontemporal_load(
              feature + (size_t)bb4.y * NCHW + coff + (size_t)(hh4.y * NW + ww4.y));
    v.z = __builtin_nontemporal_load(
              feature + (size_t)bb4.z * NCHW + coff + (size_t)(hh4.z * NW + ww4.z));
    v.w = __builtin_nontemporal_load(
              feature + (size_t)bb4.w * NCHW + coff + (size_t)(hh4.w * NW + ww4.w));
    Xq[(size_t)quad * 256 + c] = v;                  // coalesced b128 store
}

// ---------------------------------------------------------------------------
// Kernel B: 3-layer MLP. 512 blocks x 256 threads (4 waves = 2/SIMD, the
// occupancy that won in r2). Thread t -> output column t for the quad.
// Layer 1 activations are read from GLOBAL at a wave-uniform address ->
// compiler scalarizes to s_load_dwordx4; the activation is then an SGPR
// operand of v_fma (1 SGPR src allowed) -> ZERO LDS traffic in layer 1
// (r2 spent 1024 ds_read_b128 broadcasts per quad here).
// Layers 2/3 via small LDS broadcast tiles as in r2.
// Writes pq[2048][32]: rows 0..1023 = f1 @ w3, rows 1024..2047 = b3 - f2 @ w3.
// ---------------------------------------------------------------------------
__global__ __launch_bounds__(256) void mlp_kernel(
    const float4* __restrict__ Xq,
    const float* __restrict__ w1, const float* __restrict__ b1,
    const float* __restrict__ w2, const float* __restrict__ b2,
    const float* __restrict__ w3, const float* __restrict__ b3,
    float* __restrict__ pq)
{
    __shared__ float4 H1s[256];   // [j] -> 4 points, 4 KB
    __shared__ float4 F2s[128];   // [j] -> 4 points, 2 KB

    const int t = threadIdx.x;        // 0..255
    const int quad = blockIdx.x;      // 0..511
    const int base = quad * 4;
    const float4* __restrict__ Xr = Xq + (size_t)quad * 256;   // uniform base

    // ---- layer 1: 256 -> 256. thread t -> column j=t, 4 points ----
    {
        float4 acc = make_float4(0.f, 0.f, 0.f, 0.f);
        #pragma unroll 8
        for (int c = 0; c < 256; ++c) {
            const float4 a = Xr[c];             // uniform addr -> s_load_dwordx4
            const float wv = w1[c * 256 + t];   // per-lane, coalesced
            acc.x = fmaf(a.x, wv, acc.x);
            acc.y = fmaf(a.y, wv, acc.y);
            acc.z = fmaf(a.z, wv, acc.z);
            acc.w = fmaf(a.w, wv, acc.w);
        }
        const float bj = b1[t];
        float4 h;
        h.x = fmaxf(acc.x + bj, 0.f);
        h.y = fmaxf(acc.y + bj, 0.f);
        h.z = fmaxf(acc.z + bj, 0.f);
        h.w = fmaxf(acc.w + bj, 0.f);
        H1s[t] = h;                             // b128 write
    }
    __syncthreads();

    // ---- layer 2: 256 -> 128. thread t -> col j=t&127, point-pair t>>7 ----
    {
        const int j = t & 127;
        const int ph = t >> 7;                  // wave-uniform (waves 0,1 vs 2,3)
        const float* H1f = (const float*)H1s;
        float2 acc = make_float2(0.f, 0.f);
        #pragma unroll 8
        for (int c = 0; c < 256; ++c) {
            const float wv = w2[c * 128 + j];   // per-lane, coalesced
            const float2 a = *(const float2*)&H1f[c * 4 + 2 * ph];  // b64 broadcast
            acc.x = fmaf(a.x, wv, acc.x);
            acc.y = fmaf(a.y, wv, acc.y);
        }
        const float bj = b2[j];
        float* F2f = (float*)F2s;
        F2f[j * 4 + 2 * ph + 0] = fmaxf(acc.x + bj, 0.f);
        F2f[j * 4 + 2 * ph + 1] = fmaxf(acc.y + bj, 0.f);
    }
    __syncthreads();

    // ---- layer 3 (no relu): pq[g][j] = sum_c F2[g][c]*w3[c][j] ----
    if (t < 128) {
        const int j = t & 31;
        const int g = t >> 5;         // 0..3
        const float* F2f = (const float*)F2s;
        float acc = 0.f;
        #pragma unroll 8
        for (int c = 0; c < 128; ++c)
            acc = fmaf(F2f[c * 4 + g], w3[c * 32 + j], acc);
        const int point = base + g;
        const float val = (point < NPTS) ? acc : (b3[j] - acc);
        pq[(size_t)point * 32 + j] = val;   // coalesced
    }
}

// ---------------------------------------------------------------------------
// Kernel 2: out[m][n] = b4 + sum_k w4[k] * relu(p1[m][k] + q2[n][k])
// Grid: (4 n-tiles, 128 m-tiles) = 512 blocks, 256 threads (one n, 8 m's).
// P-rows and w4 are block-uniform -> scalar loads; q in VGPRs.
// Inner loop on float2 ext-vectors -> gfx950 packed fp32
// (v_pk_add/v_pk_max/v_pk_fma) halves VALU instr count; falls back to the
// identical scalar FMAs if the backend doesn't pack. Zero LDS, no barriers.
// ---------------------------------------------------------------------------
#define MT 8

__global__ __launch_bounds__(256) void pair_kernel(
    const float* __restrict__ pq,
    const float* __restrict__ w4,
    const float* __restrict__ b4,
    float* __restrict__ out)
{
    const int tid = threadIdx.x;
    const int n = blockIdx.x * 256 + tid;
    const int m0 = blockIdx.y * MT;

    // q[n][0..31] in registers via 8x dwordx4
    v2f q[16];
    const float4* q4 = (const float4*)(pq + (size_t)(NPTS + n) * 32);
    #pragma unroll
    for (int k8 = 0; k8 < 8; ++k8) {
        float4 v = q4[k8];
        q[2 * k8 + 0] = (v2f){v.x, v.y};
        q[2 * k8 + 1] = (v2f){v.z, v.w};
    }
    const float b4v = b4[0];          // uniform -> SGPR
    const v2f zero = {0.f, 0.f};

    #pragma unroll
    for (int mm = 0; mm < MT; ++mm) {
        const v2f* Pm = (const v2f*)(pq + (size_t)(m0 + mm) * 32);  // uniform -> s_load
        const v2f* w4v = (const v2f*)w4;                            // uniform -> s_load
        v2f acc = {b4v, 0.f};
        #pragma unroll
        for (int k2 = 0; k2 < 16; ++k2) {
            v2f tv = Pm[k2] + q[k2];                        // v_pk_add (sgpr+vgpr)
            v2f rv = __builtin_elementwise_max(tv, zero);   // v_pk_max
            acc = __builtin_elementwise_fma(w4v[k2], rv, acc); // v_pk_fma (sgpr mul)
        }
        out[(size_t)(m0 + mm) * 1024 + n] = acc.x + acc.y;  // coalesced over n
    }
}

extern "C" void kernel_launch(void* const* d_in, const int* in_sizes, int n_in,
                              void* d_out, int out_size, void* d_ws, size_t ws_size,
                              hipStream_t stream) {
    const float* feature = (const float*)d_in[0];
    const int*   idx1    = (const int*)d_in[1];
    const int*   idx2    = (const int*)d_in[2];
    const float* w1      = (const float*)d_in[3];
    const float* b1      = (const float*)d_in[4];
    const float* w2      = (const float*)d_in[5];
    const float* b2      = (const float*)d_in[6];
    const float* w3      = (const float*)d_in[7];
    const float* b3      = (const float*)d_in[8];
    const float* w4      = (const float*)d_in[9];
    const float* b4      = (const float*)d_in[10];
    float* out = (float*)d_out;

    float*  pq = (float*)d_ws;                                // 256 KB
    float4* Xq = (float4*)((char*)d_ws + 256 * 1024);         // 2 MB gathered acts

    gather_kernel<<<512, 256, 0, stream>>>(feature, idx1, idx2, Xq);
    mlp_kernel<<<512, 256, 0, stream>>>(Xq, w1, b1, w2, b2, w3, b3, pq);
    pair_kernel<<<dim3(4, 128), 256, 0, stream>>>(pq, w4, b4, out);
}

// Round 5
// 361.135 us; speedup vs baseline: 1.0208x; 1.0053x over previous
//
#include <hip/hip_runtime.h>

#define NPTS 1024
#define NC 256
#define NH 360
#define NW 360
#define NHW (NH * NW)
#define NCHW (NC * NHW)

typedef float v2f __attribute__((ext_vector_type(2)));

// direct HBM->LDS, 4 B/lane; dest = wave-uniform base + lane*4 (linear),
// source address is per-lane (scattered) — the supported pattern (m104).
__device__ __forceinline__ void gload_lds4(const float* g, float* lds) {
    __builtin_amdgcn_global_load_lds(
        (const __attribute__((address_space(1))) void*)g,
        (__attribute__((address_space(3))) void*)lds, 4, 0, 0);
}

// Raw barriers: do NOT use __syncthreads() (compiler emits vmcnt(0) before
// s_barrier, draining the in-flight unit-1 gathers -> kills the pipeline).
#define BAR_LDS() do { asm volatile("s_waitcnt lgkmcnt(0)" ::: "memory"); \
                       __builtin_amdgcn_s_barrier(); } while (0)
#define BAR_ALL() do { asm volatile("s_waitcnt vmcnt(0) lgkmcnt(0)" ::: "memory"); \
                       __builtin_amdgcn_s_barrier(); } while (0)
#define BAR_VM2() do { asm volatile("s_waitcnt vmcnt(2)" ::: "memory"); \
                       __builtin_amdgcn_s_barrier(); } while (0)

// ---------------------------------------------------------------------------
// Fused gather + 3-layer MLP, software-pipelined: 512 blocks x 256 threads
// (2 blocks/CU, 8 waves/CU). Block handles 4 points as 2 units x 2 points.
// All 4 gather instructions issue up front; vmcnt(2) releases unit 0 while
// unit 1's scattered HBM lines stream underneath unit 0's full compute.
// LDS layout per unit: Xs[u][c*2+pt] (float2-interleaved points) so layers
// read activations as one b128 per channel-pair.
// Writes pq[2048][32]: rows 0..1023 = f1 @ w3, rows 1024..2047 = b3 - f2 @ w3.
// ---------------------------------------------------------------------------
__global__ __launch_bounds__(256) void mlp_kernel(
    const float* __restrict__ feature,
    const int* __restrict__ idx1,
    const int* __restrict__ idx2,
    const float* __restrict__ w1, const float* __restrict__ b1,
    const float* __restrict__ w2, const float* __restrict__ b2,
    const float* __restrict__ w3, const float* __restrict__ b3,
    float* __restrict__ pq)
{
    __shared__ __align__(16) float Xs[2][512];   // [unit][c*2+pt], 4 KB
    __shared__ __align__(16) float H1s[512];     // [j*2+pt], 2 KB (reused per unit)
    __shared__ v2f  P2s[128][2];                 // layer-2 c-split partials, 2 KB
    __shared__ float F2s[256];                   // [j*2+pt], 1 KB

    const int tid = threadIdx.x;      // 0..255
    const int l   = tid & 63;         // lane
    const int wv  = tid >> 6;         // wave 0..3
    const int base = blockIdx.x * 4;

    // ---- uniform idx loads + 4 point base offsets ----
    const int col0 = base & (NPTS - 1);
    const int* idx = (base < NPTS) ? idx1 : idx2;
    const int4 bb = *(const int4*)(idx + col0);
    const int4 hh = *(const int4*)(idx + NPTS + col0);
    const int4 ww = *(const int4*)(idx + 2 * NPTS + col0);
    const size_t off0 = (size_t)bb.x * NCHW + (size_t)(hh.x * NW + ww.x);
    const size_t off1 = (size_t)bb.y * NCHW + (size_t)(hh.y * NW + ww.y);
    const size_t off2 = (size_t)bb.z * NCHW + (size_t)(hh.z * NW + ww.z);
    const size_t off3 = (size_t)bb.w * NCHW + (size_t)(hh.w * NW + ww.w);

    // ---- issue ALL gathers: unit0 (2 instrs) then unit1 (2 instrs) ----
    // lane l covers (c = chunk*32 + l/2, pt = l&1); LDS dest linear so that
    // Xs[u][chunk*64 + l] == Xs[u][c*2+pt].
    {
        const int pt = l & 1;
        const int cl = l >> 1;
        const size_t oA = pt ? off1 : off0;      // unit 0 points
        #pragma unroll
        for (int k = 0; k < 2; ++k) {
            const int chunk = wv * 2 + k;
            const int c = chunk * 32 + cl;
            gload_lds4(feature + oA + (size_t)c * NHW, &Xs[0][chunk * 64]);
        }
        const size_t oB = pt ? off3 : off2;      // unit 1 points
        #pragma unroll
        for (int k = 0; k < 2; ++k) {
            const int chunk = wv * 2 + k;
            const int c = chunk * 32 + cl;
            gload_lds4(feature + oB + (size_t)c * NHW, &Xs[1][chunk * 64]);
        }
    }

    // ---- per-unit compute stages ----
    auto layer1 = [&](const float* Xp) {         // thread t -> column t, 2 pts
        float a0 = 0.f, a1 = 0.f;
        #pragma unroll 8
        for (int c2 = 0; c2 < 128; ++c2) {
            const float4 x = *(const float4*)&Xp[c2 * 4];   // (c,p0)(c,p1)(c+1,p0)(c+1,p1)
            const float wa = w1[(2 * c2) * 256 + tid];
            const float wb = w1[(2 * c2 + 1) * 256 + tid];
            a0 = fmaf(x.x, wa, a0); a1 = fmaf(x.y, wa, a1);
            a0 = fmaf(x.z, wb, a0); a1 = fmaf(x.w, wb, a1);
        }
        const float bj = b1[tid];
        H1s[2 * tid + 0] = fmaxf(a0 + bj, 0.f);
        H1s[2 * tid + 1] = fmaxf(a1 + bj, 0.f);
    };
    auto layer2a = [&]() {                       // col j=t&127, c-half t>>7
        const int j = tid & 127;
        const int chh = tid >> 7;
        float a0 = 0.f, a1 = 0.f;
        #pragma unroll 8
        for (int c2 = 0; c2 < 64; ++c2) {
            const int c = chh * 128 + 2 * c2;
            const float4 x = *(const float4*)&H1s[2 * c];
            const float wa = w2[c * 128 + j];
            const float wb = w2[(c + 1) * 128 + j];
            a0 = fmaf(x.x, wa, a0); a1 = fmaf(x.y, wa, a1);
            a0 = fmaf(x.z, wb, a0); a1 = fmaf(x.w, wb, a1);
        }
        P2s[j][chh] = (v2f){a0, a1};
    };
    auto combine2 = [&]() {                      // reduce c-halves -> F2s
        if (tid < 128) {
            const v2f s = P2s[tid][0] + P2s[tid][1];
            const float bj = b2[tid];
            F2s[2 * tid + 0] = fmaxf(s.x + bj, 0.f);
            F2s[2 * tid + 1] = fmaxf(s.y + bj, 0.f);
        }
    };
    auto layer3 = [&](int u) {                   // 64 threads: col t&31, pt t>>5
        if (tid < 64) {
            const int j = tid & 31;
            const int pt = tid >> 5;
            float acc = 0.f;
            #pragma unroll 8
            for (int c = 0; c < 128; ++c)
                acc = fmaf(F2s[2 * c + pt], w3[c * 32 + j], acc);
            const int point = base + 2 * u + pt;
            const float val = (base < NPTS) ? acc : (b3[j] - acc);
            pq[(size_t)point * 32 + j] = val;
        }
    };

    // ---- pipelined schedule ----
    BAR_VM2();         // unit-0 LDS ready; unit-1 still in flight
    layer1(Xs[0]);     //   <- unit-1 HBM streams under all of this
    BAR_LDS();
    layer2a();
    BAR_LDS();
    combine2();
    BAR_ALL();         // F2s ready AND unit-1 gather complete
    layer3(0);
    layer1(Xs[1]);
    BAR_LDS();
    layer2a();
    BAR_LDS();
    combine2();
    BAR_LDS();
    layer3(1);
}

// ---------------------------------------------------------------------------
// Kernel 2: out[m][n] = b4 + sum_k w4[k] * relu(p1[m][k] + q2[n][k])
// Grid: (4 n-tiles, 128 m-tiles) = 512 blocks, 256 threads (one n, 8 m's).
// P-rows and w4 block-uniform -> scalar loads; q in VGPRs; packed fp32 ops.
// ---------------------------------------------------------------------------
#define MT 8

__global__ __launch_bounds__(256) void pair_kernel(
    const float* __restrict__ pq,
    const float* __restrict__ w4,
    const float* __restrict__ b4,
    float* __restrict__ out)
{
    const int tid = threadIdx.x;
    const int n = blockIdx.x * 256 + tid;
    const int m0 = blockIdx.y * MT;

    v2f q[16];
    const float4* q4 = (const float4*)(pq + (size_t)(NPTS + n) * 32);
    #pragma unroll
    for (int k8 = 0; k8 < 8; ++k8) {
        float4 v = q4[k8];
        q[2 * k8 + 0] = (v2f){v.x, v.y};
        q[2 * k8 + 1] = (v2f){v.z, v.w};
    }
    const float b4v = b4[0];
    const v2f zero = {0.f, 0.f};

    #pragma unroll
    for (int mm = 0; mm < MT; ++mm) {
        const v2f* Pm = (const v2f*)(pq + (size_t)(m0 + mm) * 32);
        const v2f* w4v = (const v2f*)w4;
        v2f acc = {b4v, 0.f};
        #pragma unroll
        for (int k2 = 0; k2 < 16; ++k2) {
            v2f tv = Pm[k2] + q[k2];
            v2f rv = __builtin_elementwise_max(tv, zero);
            acc = __builtin_elementwise_fma(w4v[k2], rv, acc);
        }
        out[(size_t)(m0 + mm) * 1024 + n] = acc.x + acc.y;
    }
}

extern "C" void kernel_launch(void* const* d_in, const int* in_sizes, int n_in,
                              void* d_out, int out_size, void* d_ws, size_t ws_size,
                              hipStream_t stream) {
    const float* feature = (const float*)d_in[0];
    const int*   idx1    = (const int*)d_in[1];
    const int*   idx2    = (const int*)d_in[2];
    const float* w1      = (const float*)d_in[3];
    const float* b1      = (const float*)d_in[4];
    const float* w2      = (const float*)d_in[5];
    const float* b2      = (const float*)d_in[6];
    const float* w3      = (const float*)d_in[7];
    const float* b3      = (const float*)d_in[8];
    const float* w4      = (const float*)d_in[9];
    const float* b4      = (const float*)d_in[10];
    float* out = (float*)d_out;

    float* pq = (float*)d_ws;                       // 2048*32*4 = 256 KB

    mlp_kernel<<<512, 256, 0, stream>>>(
        feature, idx1, idx2, w1, b1, w2, b2, w3, b3, pq);

    pair_kernel<<<dim3(4, 128), 256, 0, stream>>>(pq, w4, b4, out);
}